// Round 1
// baseline (87.300 us; speedup 1.0000x reference)
//
#include <hip/hip_runtime.h>
#include <math.h>

// Problem constants (from reference setup_inputs)
#define B_    32
#define C_    4
#define N_    16384
#define RES_  32
#define NVOX  (RES_ * RES_ * RES_)     // 32768 voxels per batch

// Main kernel tiling: CHUNKS blocks per batch, TPB threads, PTS points/thread
#define CHUNKS 32
#define TPB    256
#define PTS    (N_ / (CHUNKS * TPB))   // = 2
#define NGATH  (PTS * C_)              // 8 gathers per thread

// Workspace layout:
//   [0, B_*NVOX*16)            float4-padded cp table (16 MiB exactly)
//   [B_*NVOX*16, +B_*CHUNKS*4) partial sums
#define CP4_BYTES ((size_t)B_ * NVOX * sizeof(float4))

// Kernel 0: repack cp (B,32,32,32,3) f32 -> (B,32768) float4 in ws.
// Uses the SAME %8 XCD-swizzled batch->block mapping as sym_main, so the
// write-allocated lines of batch b land in the L2 of XCD b%8 — exactly where
// sym_main's gathers for batch b will run. This pre-warms the per-XCD L2
// (4 batches x 524KB = 2.1MB of 4MiB) right after the harness poison-fill
// flushed every cache level.
__global__ __launch_bounds__(TPB) void sym_repack(
    const float* __restrict__ cp,       // (B, RES,RES,RES, 3)
    float4* __restrict__ cp4)           // (B, NVOX)
{
  const int id   = blockIdx.x;          // B_*CHUNKS = 1024 blocks
  const int xcd  = id & 7;
  const int slot = id >> 3;
  const int b    = xcd + 8 * (slot & 3);
  const int part = slot >> 2;           // 0..31, 1024 voxels each

  const float* __restrict__ src = cp + ((size_t)b * NVOX + part * 1024) * 3;
  float4* __restrict__ dst = cp4 + (size_t)b * NVOX + part * 1024;

#pragma unroll
  for (int e = 0; e < 4; ++e) {
    const int i = e * 256 + threadIdx.x;       // consecutive lanes -> consecutive voxels
    dst[i] = make_float4(src[i * 3 + 0], src[i * 3 + 1], src[i * 3 + 2], 0.0f);
  }
}

// Kernel 1: grid = 1024 1D blocks, XCD-swizzled so each XCD (id%8 assumed)
// serves exactly 4 batches -> per-XCD gather working set 4*524KB = 2.1MB < 4MiB L2,
// and that working set was just written (warm) by sym_repack on the same XCD.
__global__ __launch_bounds__(TPB) void sym_main(
    const float* __restrict__ y_pred,   // (B, C, 4)
    const float* __restrict__ points,   // (B, N, 3)
    const float4* __restrict__ cp4,     // (B, NVOX) padded table
    float* __restrict__ partials)       // (B * CHUNKS)
{
  const int id   = blockIdx.x;
  const int xcd  = id & 7;
  const int slot = id >> 3;
  const int b     = xcd + 8 * (slot & 3);
  const int chunk = slot >> 2;

  // Plane params (uniform across block; scalar-cached loads)
  const float* yp = y_pred + b * (C_ * 4);
  float nx[C_], ny[C_], nz[C_], dd[C_];
#pragma unroll
  for (int c = 0; c < C_; ++c) {
    float ax = yp[c * 4 + 0];
    float ay = yp[c * 4 + 1];
    float az = yp[c * 4 + 2];
    float inv = 1.0f / sqrtf(ax * ax + ay * ay + az * az);
    nx[c] = ax * inv;
    ny[c] = ay * inv;
    nz[c] = az * inv;
    dd[c] = yp[c * 4 + 3];
  }

  const float* pb = points + (size_t)b * (N_ * 3);
  const float4* __restrict__ cpb4 = cp4 + (size_t)b * NVOX;

  const int t = chunk * TPB + threadIdx.x;

  // Phase 1: load points, compute all reflected vectors + gather indices.
  float rx[NGATH], ry[NGATH], rz[NGATH];
  int lin[NGATH];
#pragma unroll
  for (int k = 0; k < PTS; ++k) {
    const int p = t + k * (CHUNKS * TPB);
    const float px = pb[p * 3 + 0];
    const float py = pb[p * 3 + 1];
    const float pz = pb[p * 3 + 2];
#pragma unroll
    for (int c = 0; c < C_; ++c) {
      const int g = k * C_ + c;
      float dist = px * nx[c] + py * ny[c] + pz * nz[c] + dd[c];
      float t2 = 2.0f * dist;
      float x = px - t2 * nx[c];
      float y = py - t2 * ny[c];
      float z = pz - t2 * nz[c];
      rx[g] = x; ry[g] = y; rz[g] = z;
      int vx = (int)fminf(fmaxf(floorf(x * (float)RES_), 0.0f), (float)(RES_ - 1));
      int vy = (int)fminf(fmaxf(floorf(y * (float)RES_), 0.0f), (float)(RES_ - 1));
      int vz = (int)fminf(fmaxf(floorf(z * (float)RES_), 0.0f), (float)(RES_ - 1));
      lin[g] = (vx * RES_ + vy) * RES_ + vz;   // float4 element index
    }
  }

  // Phase 2: issue all 8 gathers, each a single 16B-aligned global_load_dwordx4
  // (exactly one 64B line per lane, never split), all outstanding simultaneously.
  float cx[NGATH], cy[NGATH], cz[NGATH];
#pragma unroll
  for (int g = 0; g < NGATH; ++g) {
    const float4 v = cpb4[lin[g]];
    cx[g] = v.x; cy[g] = v.y; cz[g] = v.z;
  }

  // Phase 3: distances into 4 independent accumulators (break sqrt chain).
  float a0 = 0.0f, a1 = 0.0f, a2 = 0.0f, a3 = 0.0f;
#pragma unroll
  for (int g = 0; g < NGATH; g += 4) {
    float dx0 = rx[g+0] - cx[g+0], dy0 = ry[g+0] - cy[g+0], dz0 = rz[g+0] - cz[g+0];
    float dx1 = rx[g+1] - cx[g+1], dy1 = ry[g+1] - cy[g+1], dz1 = rz[g+1] - cz[g+1];
    float dx2 = rx[g+2] - cx[g+2], dy2 = ry[g+2] - cy[g+2], dz2 = rz[g+2] - cz[g+2];
    float dx3 = rx[g+3] - cx[g+3], dy3 = ry[g+3] - cy[g+3], dz3 = rz[g+3] - cz[g+3];
    a0 += sqrtf(dx0 * dx0 + dy0 * dy0 + dz0 * dz0);
    a1 += sqrtf(dx1 * dx1 + dy1 * dy1 + dz1 * dz1);
    a2 += sqrtf(dx2 * dx2 + dy2 * dy2 + dz2 * dz2);
    a3 += sqrtf(dx3 * dx3 + dy3 * dy3 + dz3 * dz3);
  }
  float acc = (a0 + a1) + (a2 + a3);

  // Wave (64-lane) shuffle reduction, then cross-wave via LDS
#pragma unroll
  for (int off = 32; off > 0; off >>= 1)
    acc += __shfl_down(acc, off, 64);

  __shared__ float sred[TPB / 64];
  const int lane = threadIdx.x & 63;
  const int wave = threadIdx.x >> 6;
  if (lane == 0) sred[wave] = acc;
  __syncthreads();
  if (threadIdx.x == 0) {
    float tot = 0.0f;
#pragma unroll
    for (int w = 0; w < TPB / 64; ++w) tot += sred[w];
    partials[b * CHUNKS + chunk] = tot;
  }
}

// Kernel 2: single block. Sums the B*CHUNKS partials (fp64 accumulate for
// precision: raw sum is ~5e6), adds REG_COEF * mean_b(reg_loss[b]).
__global__ __launch_bounds__(256) void sym_final(
    const float* __restrict__ y_pred,
    const float* __restrict__ partials,
    float* __restrict__ out)
{
  __shared__ double sd[256];
  double acc = 0.0;
  for (int i = threadIdx.x; i < B_ * CHUNKS; i += 256)
    acc += (double)partials[i];
  acc *= (1.0 / (double)N_);   // mean over n folded into the b,c sum

  if (threadIdx.x < B_) {
    const int b = threadIdx.x;
    const float* yp = y_pred + b * (C_ * 4);
    float nh[C_][3];
#pragma unroll
    for (int c = 0; c < C_; ++c) {
      float ax = yp[c * 4 + 0];
      float ay = yp[c * 4 + 1];
      float az = yp[c * 4 + 2];
      float inv = 1.0f / sqrtf(ax * ax + ay * ay + az * az);
      nh[c][0] = ax * inv;
      nh[c][1] = ay * inv;
      nh[c][2] = az * inv;
    }
    float s = 0.0f;
#pragma unroll
    for (int c = 0; c < C_; ++c) {
#pragma unroll
      for (int e = 0; e < C_; ++e) {
        float dot = nh[c][0] * nh[e][0] + nh[c][1] * nh[e][1] + nh[c][2] * nh[e][2];
        float g = dot - ((c == e) ? 1.0f : 0.0f);
        s += g * g;
      }
    }
    acc += (25.0 / (double)B_) * (double)sqrtf(s);
  }

  sd[threadIdx.x] = acc;
  __syncthreads();
  for (int off = 128; off > 0; off >>= 1) {
    if (threadIdx.x < off) sd[threadIdx.x] += sd[threadIdx.x + off];
    __syncthreads();
  }
  if (threadIdx.x == 0) out[0] = (float)sd[0];
}

extern "C" void kernel_launch(void* const* d_in, const int* in_sizes, int n_in,
                              void* d_out, int out_size, void* d_ws, size_t ws_size,
                              hipStream_t stream) {
  const float* y_pred = (const float*)d_in[0];   // (32,4,4)
  const float* points = (const float*)d_in[1];   // (32,16384,3)
  // d_in[2] = voxel_grid — unused by the reference loss
  const float* cp     = (const float*)d_in[3];   // (32,32,32,32,3)

  float4* cp4     = (float4*)d_ws;
  float* partials = (float*)((char*)d_ws + CP4_BYTES);
  float* out = (float*)d_out;

  sym_repack<<<B_ * CHUNKS, TPB, 0, stream>>>(cp, cp4);
  sym_main<<<B_ * CHUNKS, TPB, 0, stream>>>(y_pred, points, cp4, partials);
  sym_final<<<1, 256, 0, stream>>>(y_pred, partials, out);
}